// Round 1
// baseline (32940.442 us; speedup 1.0000x reference)
//
#include <hip/hip_runtime.h>
#include <math.h>

#define T_STEPS 2048
#define BATCH   64
#define IDIM    256
#define HDIM    512
#define K1      768
#define H3      1536
#define NGROUP  4
#define NSLICE  32
#define RPG     16
#define THREADS 512

// ---------------------------------------------------------------------------
// Data-as-stamp sync protocol (replaces stamp publish/poll):
//   Every cross-block buffer is a 3-phase rotating buffer (phase = t % 3),
//   pre-poisoned with a NaN pattern. Producers store data directly with
//   relaxed agent-scope 64/32-bit atomic stores (atomic pairs -> no tearing);
//   consumers poll the DATA until non-poison. This removes, per sync, the
//   stamp-store->stamp-poll LLC round trip AND the dependent data load AND
//   the publish barrier. 4 syncs/step * 2048 steps.
//   Re-poison schedule (each block poisons ONLY its own slice):
//     a1,a2,p3: poison phase (t+2)%3 at production time (stages 1/2/3 of t)
//     cb      : poison phase (t+1)%3 in the epilogue of t
//   Safety: block X producing step-t data implies (by stage-chain causality)
//   all blocks finished reading the poisoned phase; X's poison stores are
//   drained by its later __syncthreads (vmcnt(0)) long before any rewrite.
//   Poison pattern 0x7FC07FC0 is NaN as f32 and NaN|NaN as a bf16 pair; all
//   legit values (bounded GEMM sums, s2>=0, finite c) can never equal it.
// ---------------------------------------------------------------------------
#define POISON_U 0x7FC07FC0u

// dword-unit workspace offsets
#define A1_PH   32768       // 64 rows * 512 f32 per phase
#define OFF_A1  0           // 3 phases
#define OFF_A2  98304       // 3 phases
#define CB_PH   16384       // 64 rows * 256 uint (bf16 pairs) per phase
#define OFF_CB  196608      // 3 phases
#define P3_PH   4096        // 64 rows * 32 slices * 2 f32 per phase
#define OFF_P3  245760      // 3 phases
#define WS_DWORDS 258048    // ~1.01 MB total

typedef __attribute__((ext_vector_type(8))) __bf16 bf16x8;
typedef __attribute__((ext_vector_type(4))) float f32x4;

__device__ __forceinline__ f32x4 MFMA(bf16x8 a, bf16x8 b, f32x4 c) {
    return __builtin_amdgcn_mfma_f32_16x16x32_bf16(a, b, c, 0, 0, 0);
}

__device__ __forceinline__ float2 gload2(const float* p) {
    unsigned long long v = __hip_atomic_load((const unsigned long long*)p,
                                             __ATOMIC_RELAXED, __HIP_MEMORY_SCOPE_AGENT);
    return __builtin_bit_cast(float2, v);
}
__device__ __forceinline__ void gstore2(float* p, float a, float b) {
    float2 v = {a, b};
    __hip_atomic_store((unsigned long long*)p, __builtin_bit_cast(unsigned long long, v),
                       __ATOMIC_RELAXED, __HIP_MEMORY_SCOPE_AGENT);
}
__device__ __forceinline__ unsigned gload_u(const unsigned* p) {
    return __hip_atomic_load(p, __ATOMIC_RELAXED, __HIP_MEMORY_SCOPE_AGENT);
}
__device__ __forceinline__ void gstore_u(unsigned* p, unsigned v) {
    __hip_atomic_store(p, v, __ATOMIC_RELAXED, __HIP_MEMORY_SCOPE_AGENT);
}

struct bf16pair { __bf16 hi, lo; };
__device__ __forceinline__ bf16pair split2(float f) {
    bf16pair r;
    r.hi = (__bf16)f;
    r.lo = (__bf16)(f - (float)r.hi);
    return r;
}
__device__ __forceinline__ unsigned pk2(float a, float b) {
    return (unsigned)__builtin_bit_cast(unsigned short, (__bf16)a) |
           ((unsigned)__builtin_bit_cast(unsigned short, (__bf16)b) << 16);
}
__device__ __forceinline__ void st_pair(__bf16* p, __bf16 a, __bf16 b) {
    unsigned v = (unsigned)__builtin_bit_cast(unsigned short, a) |
                 ((unsigned)__builtin_bit_cast(unsigned short, b) << 16);
    *(unsigned*)p = v;
}
__device__ __forceinline__ float elu1(float v) {
    return v > 0.f ? v : (expf(v) - 1.f);
}

__global__ void dlstm_init(float* __restrict__ ws) {
    unsigned* w = (unsigned*)ws;
    for (unsigned i = blockIdx.x * blockDim.x + threadIdx.x; i < WS_DWORDS;
         i += gridDim.x * blockDim.x)
        w[i] = POISON_U;
}

__global__ __launch_bounds__(THREADS, 2) void dlstm_main(
    const float* __restrict__ x,
    const float* __restrict__ W1, const float* __restrict__ g1, const float* __restrict__ b1,
    const float* __restrict__ W2, const float* __restrict__ g2, const float* __restrict__ b2,
    const float* __restrict__ W3, const float* __restrict__ g3, const float* __restrict__ b3,
    float* __restrict__ out, float* __restrict__ ws)
{
    const int tid = threadIdx.x;
    const int bid = blockIdx.x;
    const int g = bid & 3;
    const int s = bid >> 2;          // 0..31 feature slice
    const int r0 = g * RPG;

    const int lane = tid & 63;
    const int wv   = tid >> 6;       // wave 0..7 (k-split)
    const int col  = lane & 15;
    const int kq   = lane >> 4;
    const int er   = tid >> 5;       // row 0..15 for elementwise phases
    const int l32  = tid & 31;

    float*    a1base = ws + OFF_A1;
    float*    a2base = ws + OFF_A2;
    unsigned* cbbase = (unsigned*)ws + OFF_CB;
    float*    p3base = ws + OFF_P3;

    __shared__ __bf16 zh[16][776];   // 388 dwords/row, 388%32==4
    __shared__ float comb[8][3][256];
    __shared__ float slab[16][48];   // [i|16+i|32+i] = gates h,c,f
    __shared__ float stats[16][2];

    const float qnan = __builtin_bit_cast(float, POISON_U);

    // ---------------- hoisted LN params (loop-invariant) ----------------
    float2 g1v[8], b1v[8], g2v[8], b2v[8];
    #pragma unroll
    for (int j = 0; j < 8; ++j) {
        int k = j * 64 + l32 * 2;
        g1v[j] = *(const float2*)(g1 + k); b1v[j] = *(const float2*)(b1 + k);
        g2v[j] = *(const float2*)(g2 + k); b2v[j] = *(const float2*)(b2 + k);
    }
    // epilogue threads: tid<128 handle (row = tid>>3, cols 16s+2j, 16s+2j+1)
    float2 g3h2 = {0,0}, b3h2 = {0,0}, g3c2 = {0,0}, b3c2 = {0,0}, g3f2 = {0,0}, b3f2 = {0,0};
    if (tid < 128) {
        int j = tid & 7; int h0 = 16 * s + 2 * j;
        g3h2 = *(const float2*)(g3 + h0);            b3h2 = *(const float2*)(b3 + h0);
        g3c2 = *(const float2*)(g3 + HDIM + h0);     b3c2 = *(const float2*)(b3 + HDIM + h0);
        g3f2 = *(const float2*)(g3 + 2 * HDIM + h0); b3f2 = *(const float2*)(b3 + 2 * HDIM + h0);
    }

    // ---------------- weights -> register fragments (hi/lo split) ----------------
    bf16x8 w1h[3], w1l[3], w2h[2], w2l[2], w3h[3][2], w3l[3][2];
    #pragma unroll
    for (int ks = 0; ks < 3; ++ks) {
        int k0 = wv * 96 + ks * 32 + kq * 8;
        const float* p = W1 + (size_t)(16 * s + col) * K1 + k0;
        #pragma unroll
        for (int e = 0; e < 8; ++e) {
            bf16pair pr = split2(p[e]);
            w1h[ks][e] = pr.hi; w1l[ks][e] = pr.lo;
        }
    }
    #pragma unroll
    for (int ks = 0; ks < 2; ++ks) {
        int k0 = wv * 64 + ks * 32 + kq * 8;
        const float* p = W2 + (size_t)(16 * s + col) * HDIM + k0;
        #pragma unroll
        for (int e = 0; e < 8; ++e) {
            bf16pair pr = split2(p[e]);
            w2h[ks][e] = pr.hi; w2l[ks][e] = pr.lo;
        }
    }
    #pragma unroll
    for (int tb = 0; tb < 3; ++tb) {
        #pragma unroll
        for (int ks = 0; ks < 2; ++ks) {
            int k0 = wv * 64 + ks * 32 + kq * 8;
            const float* p = W3 + (size_t)(tb * HDIM + 16 * s + col) * HDIM + k0;
            #pragma unroll
            for (int e = 0; e < 8; ++e) {
                bf16pair pr = split2(p[e]);
                w3h[tb][ks][e] = pr.hi; w3l[tb][ks][e] = pr.lo;
            }
        }
    }

    // distributed cell state: thread tid<128 owns c[row = tid>>3][cols 16s+2(tid&7)+{0,1}]
    float cr0 = 0.f, cr1 = 0.f;

    // prefetch + pre-pack x for t=0
    float2 xr[4];
    unsigned xb[4];
    {
        const float* xrow = x + (size_t)(r0 + er) * IDIM;
        #pragma unroll
        for (int j = 0; j < 4; ++j) xr[j] = *(const float2*)(xrow + j * 64 + l32 * 2);
        #pragma unroll
        for (int j = 0; j < 4; ++j) xb[j] = pk2(xr[j].x, xr[j].y);
    }

    #pragma unroll 1
    for (int t = 0; t < T_STEPS; ++t) {
        const int ph  = t % 3;
        const int ph1 = (ph == 2) ? 0 : ph + 1;   // (t+1)%3
        const int ph2 = (ph == 0) ? 2 : ph - 1;   // (t+2)%3 == (t-1)%3

        float*    a1w = a1base + ph  * A1_PH;
        float*    a1p = a1base + ph2 * A1_PH;
        float*    a2w = a2base + ph  * A1_PH;
        float*    a2p = a2base + ph2 * A1_PH;
        unsigned* cbw = cbbase + ph  * CB_PH;
        unsigned* cbp = cbbase + ph1 * CB_PH;
        const unsigned* cbr = cbbase + ph2 * CB_PH;   // produced at t-1
        float*    p3w = p3base + ph  * P3_PH;
        float*    p3p = p3base + ph2 * P3_PH;

        unsigned* zrow = (unsigned*)&zh[er][0];
        // ================= stage 1: x-plane + GEMM1(x part) =================
        #pragma unroll
        for (int j = 0; j < 4; ++j) zrow[j * 32 + l32] = xb[j];
        __syncthreads();                                              // b1
        f32x4 acc = {0.f, 0.f, 0.f, 0.f};
        #pragma unroll
        for (int ks = 0; ks < 3; ++ks) {
            int kb = wv * 96 + ks * 32;
            if (kb < IDIM) {
                bf16x8 ah = *(const bf16x8*)&zh[col][kb + kq * 8];
                acc = MFMA(ah, w1h[ks], acc);
                acc = MFMA(ah, w1l[ks], acc);
            }
        }
        // ---- c exchange: poll the bf16-pair data itself (no stamps) ----
        if (t > 0) {
            const unsigned* cbrow = cbr + (size_t)(r0 + er) * (HDIM / 2);
            unsigned vb[8]; unsigned m = 0xffu;
            while (true) {
                #pragma unroll
                for (int j = 0; j < 8; ++j)
                    if (m & (1u << j)) {
                        vb[j] = gload_u(cbrow + j * 32 + l32);
                        if (vb[j] != POISON_U) m &= ~(1u << j);
                    }
                if (__all(m == 0)) break;
                __builtin_amdgcn_s_sleep(1);
            }
            #pragma unroll
            for (int j = 0; j < 8; ++j) zrow[128 + j * 32 + l32] = vb[j];
        } else {
            #pragma unroll
            for (int j = 0; j < 8; ++j) zrow[128 + j * 32 + l32] = 0u;
        }
        __syncthreads();                                              // b2
        #pragma unroll
        for (int ks = 0; ks < 3; ++ks) {
            int kb = wv * 96 + ks * 32;
            if (kb >= IDIM) {
                bf16x8 ah = *(const bf16x8*)&zh[col][kb + kq * 8];
                acc = MFMA(ah, w1h[ks], acc);
                acc = MFMA(ah, w1l[ks], acc);
            }
        }
        #pragma unroll
        for (int i = 0; i < 4; ++i) comb[wv][0][(kq * 4 + i) * 16 + col] = acc[i];
        __syncthreads();                                              // b3
        if (tid < 128) {
            int r = tid >> 3, fp = tid & 7;
            int i0 = r * 16 + fp * 2;
            float v0 = 0.f, v1 = 0.f;
            #pragma unroll
            for (int w = 0; w < 8; ++w) { v0 += comb[w][0][i0]; v1 += comb[w][0][i0 + 1]; }
            size_t o = (size_t)(r0 + r) * HDIM + 16 * s + fp * 2;
            gstore2(a1w + o, v0, v1);        // data IS the stamp
            gstore2(a1p + o, qnan, qnan);    // re-poison phase (t+2)%3
        }
        // no publish barrier

        // ================= stage 2: h1 = elu(LN(a1)); GEMM2 =================
        {
            const float* arow = a1w + (size_t)(r0 + er) * HDIM;
            float2 va[8]; unsigned m = 0xffu;
            while (true) {
                #pragma unroll
                for (int j = 0; j < 8; ++j)
                    if (m & (1u << j)) {
                        va[j] = gload2(arow + j * 64 + l32 * 2);
                        if (va[j].x == va[j].x) m &= ~(1u << j);   // 64b atomic pair: x clean => pair clean
                    }
                if (__all(m == 0)) break;
                __builtin_amdgcn_s_sleep(1);
            }
            float s1 = 0.f, s2 = 0.f;
            #pragma unroll
            for (int j = 0; j < 8; ++j) {
                s1 += va[j].x + va[j].y; s2 += va[j].x * va[j].x + va[j].y * va[j].y;
            }
            s1 += __shfl_xor(s1, 1, 64); s2 += __shfl_xor(s2, 1, 64);
            s1 += __shfl_xor(s1, 2, 64); s2 += __shfl_xor(s2, 2, 64);
            s1 += __shfl_xor(s1, 4, 64); s2 += __shfl_xor(s2, 4, 64);
            s1 += __shfl_xor(s1, 8, 64); s2 += __shfl_xor(s2, 8, 64);
            s1 += __shfl_xor(s1, 16, 64); s2 += __shfl_xor(s2, 16, 64);
            float mu = s1 * (1.f / HDIM);
            float var = s2 * (1.f / HDIM) - mu * mu;
            float rs = rsqrtf(var + 1e-5f);
            #pragma unroll
            for (int j = 0; j < 8; ++j) {
                int k = j * 64 + l32 * 2;
                float v0 = elu1((va[j].x - mu) * rs * g1v[j].x + b1v[j].x);
                float v1 = elu1((va[j].y - mu) * rs * g1v[j].y + b1v[j].y);
                st_pair(&zh[er][k], (__bf16)v0, (__bf16)v1);
            }
        }
        __syncthreads();                                              // b5
        {
            f32x4 acc2 = {0.f, 0.f, 0.f, 0.f};
            #pragma unroll
            for (int ks = 0; ks < 2; ++ks) {
                int k0 = wv * 64 + ks * 32 + kq * 8;
                bf16x8 ah = *(const bf16x8*)&zh[col][k0];
                acc2 = MFMA(ah, w2h[ks], acc2);
                acc2 = MFMA(ah, w2l[ks], acc2);
            }
            #pragma unroll
            for (int i = 0; i < 4; ++i) comb[wv][0][(kq * 4 + i) * 16 + col] = acc2[i];
        }
        __syncthreads();                                              // b6
        if (tid < 128) {
            int r = tid >> 3, fp = tid & 7;
            int i0 = r * 16 + fp * 2;
            float v0 = 0.f, v1 = 0.f;
            #pragma unroll
            for (int w = 0; w < 8; ++w) { v0 += comb[w][0][i0]; v1 += comb[w][0][i0 + 1]; }
            size_t o = (size_t)(r0 + r) * HDIM + 16 * s + fp * 2;
            gstore2(a2w + o, v0, v1);
            gstore2(a2p + o, qnan, qnan);
        }

        // ================= stage 3: h2 = elu(LN(a2)); prefetch x(t+1); GEMM3 =================
        {
            {   // prefetch next x first: overlaps the a2 poll below
                int tn = (t + 1 < T_STEPS) ? t + 1 : t;
                const float* xrow = x + ((size_t)tn * BATCH + r0 + er) * IDIM;
                #pragma unroll
                for (int j = 0; j < 4; ++j) xr[j] = *(const float2*)(xrow + j * 64 + l32 * 2);
            }
            const float* arow = a2w + (size_t)(r0 + er) * HDIM;
            float2 va[8]; unsigned m = 0xffu;
            while (true) {
                #pragma unroll
                for (int j = 0; j < 8; ++j)
                    if (m & (1u << j)) {
                        va[j] = gload2(arow + j * 64 + l32 * 2);
                        if (va[j].x == va[j].x) m &= ~(1u << j);
                    }
                if (__all(m == 0)) break;
                __builtin_amdgcn_s_sleep(1);
            }
            float s1 = 0.f, s2 = 0.f;
            #pragma unroll
            for (int j = 0; j < 8; ++j) {
                s1 += va[j].x + va[j].y; s2 += va[j].x * va[j].x + va[j].y * va[j].y;
            }
            s1 += __shfl_xor(s1, 1, 64); s2 += __shfl_xor(s2, 1, 64);
            s1 += __shfl_xor(s1, 2, 64); s2 += __shfl_xor(s2, 2, 64);
            s1 += __shfl_xor(s1, 4, 64); s2 += __shfl_xor(s2, 4, 64);
            s1 += __shfl_xor(s1, 8, 64); s2 += __shfl_xor(s2, 8, 64);
            s1 += __shfl_xor(s1, 16, 64); s2 += __shfl_xor(s2, 16, 64);
            float mu = s1 * (1.f / HDIM);
            float var = s2 * (1.f / HDIM) - mu * mu;
            float rs = rsqrtf(var + 1e-5f);
            #pragma unroll
            for (int j = 0; j < 8; ++j) {
                int k = j * 64 + l32 * 2;
                float v0 = elu1((va[j].x - mu) * rs * g2v[j].x + b2v[j].x);
                float v1 = elu1((va[j].y - mu) * rs * g2v[j].y + b2v[j].y);
                st_pair(&zh[er][k], (__bf16)v0, (__bf16)v1);
            }
        }
        __syncthreads();                                              // b8
        {
            f32x4 acc0 = {0.f,0.f,0.f,0.f}, acc1 = {0.f,0.f,0.f,0.f}, acc2 = {0.f,0.f,0.f,0.f};
            #pragma unroll
            for (int ks = 0; ks < 2; ++ks) {
                int k0 = wv * 64 + ks * 32 + kq * 8;
                bf16x8 ah = *(const bf16x8*)&zh[col][k0];
                acc0 = MFMA(ah, w3h[0][ks], acc0);
                acc0 = MFMA(ah, w3l[0][ks], acc0);
                acc1 = MFMA(ah, w3h[1][ks], acc1);
                acc1 = MFMA(ah, w3l[1][ks], acc1);
                acc2 = MFMA(ah, w3h[2][ks], acc2);
                acc2 = MFMA(ah, w3l[2][ks], acc2);
            }
            #pragma unroll
            for (int i = 0; i < 4; ++i) {
                comb[wv][0][(kq * 4 + i) * 16 + col] = acc0[i];
                comb[wv][1][(kq * 4 + i) * 16 + col] = acc1[i];
                comb[wv][2][(kq * 4 + i) * 16 + col] = acc2[i];
            }
        }
        __syncthreads();                                              // b9
        if (tid < 384) {             // reduce into LDS slab only
            int o = tid * 2;
            int tb = o >> 8, idx = o & 255;
            int r = idx >> 4, f0 = idx & 15;
            float v0 = 0.f, v1 = 0.f;
            #pragma unroll
            for (int w = 0; w < 8; ++w) { v0 += comb[w][tb][idx]; v1 += comb[w][tb][idx + 1]; }
            slab[r][tb * 16 + f0] = v0;
            slab[r][tb * 16 + f0 + 1] = v1;
        }
        __syncthreads();                                              // b10
        {
            float va_ = slab[er][l32];
            float vb_ = (l32 < 16) ? slab[er][32 + l32] : 0.f;
            float s1 = va_ + vb_;
            float s2 = va_ * va_ + vb_ * vb_;
            s1 += __shfl_xor(s1, 1, 64); s2 += __shfl_xor(s2, 1, 64);
            s1 += __shfl_xor(s1, 2, 64); s2 += __shfl_xor(s2, 2, 64);
            s1 += __shfl_xor(s1, 4, 64); s2 += __shfl_xor(s2, 4, 64);
            s1 += __shfl_xor(s1, 8, 64); s2 += __shfl_xor(s2, 8, 64);
            s1 += __shfl_xor(s1, 16, 64); s2 += __shfl_xor(s2, 16, 64);
            if (l32 == 0) {
                size_t o = ((size_t)(r0 + er) * NSLICE + s) * 2;
                gstore2(p3w + o, s1, s2);      // s2 >= 0, s1 finite: never NaN
                gstore2(p3p + o, qnan, qnan);
            }
        }

        // ================= epilogue (distributed): LN3 stats, own-slice gates, c update =================
        {
            const float* pp = p3w + ((size_t)(r0 + er) * NSLICE + l32) * 2;
            float2 pv;
            while (true) {
                pv = gload2(pp);
                if (__all(pv.x == pv.x)) break;
                __builtin_amdgcn_s_sleep(1);
            }
            float s1 = pv.x, s2 = pv.y;
            s1 += __shfl_xor(s1, 1, 64); s2 += __shfl_xor(s2, 1, 64);
            s1 += __shfl_xor(s1, 2, 64); s2 += __shfl_xor(s2, 2, 64);
            s1 += __shfl_xor(s1, 4, 64); s2 += __shfl_xor(s2, 4, 64);
            s1 += __shfl_xor(s1, 8, 64); s2 += __shfl_xor(s2, 8, 64);
            s1 += __shfl_xor(s1, 16, 64); s2 += __shfl_xor(s2, 16, 64);
            float mu = s1 * (1.f / H3);
            float var = s2 * (1.f / H3) - mu * mu;
            float rs = rsqrtf(var + 1e-5f);
            if (l32 == 0) { stats[er][0] = mu; stats[er][1] = rs; }
        }
        __syncthreads();                                              // b12
        if (tid < 128) {
            int r = tid >> 3, j = tid & 7;
            int i0 = 2 * j;
            float mu = stats[r][0], rs = stats[r][1];
            float oh0 = (slab[r][i0]          - mu) * rs * g3h2.x + b3h2.x;
            float oh1 = (slab[r][i0 + 1]      - mu) * rs * g3h2.y + b3h2.y;
            float oc0 = (slab[r][16 + i0]     - mu) * rs * g3c2.x + b3c2.x;
            float oc1 = (slab[r][16 + i0 + 1] - mu) * rs * g3c2.y + b3c2.y;
            float of0 = (slab[r][32 + i0]     - mu) * rs * g3f2.x + b3f2.x;
            float of1 = (slab[r][32 + i0 + 1] - mu) * rs * g3f2.y + b3f2.y;
            float sg0 = 1.f / (1.f + expf(-of0)); float f0 = sg0 * sg0;
            float sg1 = 1.f / (1.f + expf(-of1)); float f1 = sg1 * sg1;
            float cn0 = f0 * elu1(oc0) + (1.f - f0) * cr0;
            float cn1 = f1 * elu1(oc1) + (1.f - f1) * cr1;
            cr0 = cn0; cr1 = cn1;
            // cb pair store first: it is the recurrence-critical data for t+1
            size_t co = (size_t)(r0 + r) * (HDIM / 2) + 8 * s + j;
            gstore_u(cbw + co, pk2(cn0, cn1));
            gstore_u(cbp + co, POISON_U);      // poison phase (t+1)%3
            // out[] HBM stores AFTER the critical stores (pure sink)
            float2 ho = { elu1(oh0), elu1(oh1) };
            *(float2*)(out + ((size_t)t * BATCH + r0 + r) * HDIM + 16 * s + i0) = ho;
            if (t == T_STEPS - 1) {
                float2 cf = { cn0, cn1 };
                *(float2*)(out + (size_t)T_STEPS * BATCH * HDIM
                               + (size_t)(r0 + r) * HDIM + 16 * s + i0) = cf;
            }
        }
        // pack next-step x (loads issued in stage 3 are long since complete)
        #pragma unroll
        for (int j = 0; j < 4; ++j) xb[j] = pk2(xr[j].x, xr[j].y);
        // no end-of-step barrier: next-iter zh x-writes only race with stage-3
        // MFMA reads, which every thread finished before b9
    }
}

extern "C" void kernel_launch(void* const* d_in, const int* in_sizes, int n_in,
                              void* d_out, int out_size, void* d_ws, size_t ws_size,
                              hipStream_t stream) {
    const float* x  = (const float*)d_in[0];
    const float* W1 = (const float*)d_in[1];
    const float* g1 = (const float*)d_in[2];
    const float* b1 = (const float*)d_in[3];
    const float* W2 = (const float*)d_in[4];
    const float* g2 = (const float*)d_in[5];
    const float* b2 = (const float*)d_in[6];
    const float* W3 = (const float*)d_in[7];
    const float* g3 = (const float*)d_in[8];
    const float* b3 = (const float*)d_in[9];
    float* out = (float*)d_out;
    float* ws  = (float*)d_ws;

    dlstm_init<<<256, 256, 0, stream>>>(ws);
    dlstm_main<<<NGROUP * NSLICE, THREADS, 0, stream>>>(x, W1, g1, b1, W2, g2, b2, W3, g3, b3, out, ws);
}